// Round 8
// baseline (176.739 us; speedup 1.0000x reference)
//
#include <hip/hip_runtime.h>
#include <hip/hip_bf16.h>

// SNN: conv1(3->64,3x3,p1)+LIF -> conv2(64->64,3x3,p1)+LIF -> FC(65536->10), sum T=8.
// LIF non-recurrent: spike = (pre >= 1.2f).
// conv1: bf16 MFMA 16x16x32, exact 4-term split (xh+xl)(wh+wl), K=27->32 (zero weights).
// conv2: i8 MFMA 16x16x64, 2-term i8 weights (q1+q2; s2=s1/254), spikes exact i8.
// R8: conv2 waves shrunk to 16 co (Bf 72 VGPR) -> <=128 regs -> 4 waves/SIMD, grid 512,
//     2 blocks/CU; XOR-skewed cnt bounce (no 16-way conflicts); setprio around MFMA.
//     conv1 split into row-halves (grid 1024, 4 blocks/CU). fc: 64 ig x 8 bg, wave-per-2b.

typedef __attribute__((ext_vector_type(8))) short bf16x8;
typedef __attribute__((ext_vector_type(4))) float f32x4;
typedef __attribute__((ext_vector_type(4))) int   i32x4;

#define S1Q (5.5f/127.0f)       // q1 scale (max|N(0,1)| over 36864 < 5.5 w.p. ~1)
#define S2Q (S1Q/254.0f)        // q2 scale (resid <= s1/2 -> q2 <= 127)

// ws layout
static const size_t SZ_IMG  = 65536;                 // 32*32*64 i8, unpadded spike image
static const size_t OFF_S8  = 0;                     // [512 img] = 33,554,432 B
static const size_t OFF_CNT = 512*SZ_IMG;            // u8 [64b][64co][1024] = 4 MiB
static const size_t OFF_W1F = OFF_CNT + (4u<<20);    // bf16 [2][64co][32k] = 8192 B
static const size_t OFF_BQ  = OFF_W1F + 8192;        // i8 [2q][9s][64co][64ci] = 73,728 B

#define SWZ(cp) (((cp) >> 1) & 3)

__device__ __forceinline__ void gl_lds16(const void* g, void* l) {
  __builtin_amdgcn_global_load_lds(
      (const __attribute__((address_space(1))) unsigned int*)g,
      (__attribute__((address_space(3))) unsigned int*)l, 16, 0, 0);
}

// ---- prep: conv1 weights bf16 hi/lo; conv2 weights 2-term i8
__global__ __launch_bounds__(256) void kprep(
    const float* __restrict__ w1, const float* __restrict__ w2,
    short* __restrict__ W1F, signed char* __restrict__ Bq)
{
  int i = blockIdx.x*256 + threadIdx.x;
  if (i < 4096) {                       // W1F[t2][co][k]
    int t2 = i >> 11, r = i & 2047, co = r >> 5, k = r & 31;
    short out = 0;
    if (k < 27) {
      int s = k/3, ci = k - s*3;
      float w = w1[co*27 + ci*9 + s];
      __hip_bfloat16 h = __float2bfloat16(w);
      if (t2 == 0) out = *(short*)&h;
      else { __hip_bfloat16 lo = __float2bfloat16(w - (float)h); out = *(short*)&lo; }
    }
    W1F[i] = out;
  }
  if (i < 36864) {                      // Bq[q][s][co][ci]
    int co = i/576, rem = i - co*576, ci = rem/9, s = rem - ci*9;
    float w = w2[i];
    int q1 = (int)roundf(w * (1.0f/S1Q)); q1 = q1 > 127 ? 127 : (q1 < -127 ? -127 : q1);
    float r1 = w - S1Q*(float)q1;
    int q2 = (int)roundf(r1 * (1.0f/S2Q)); q2 = q2 > 127 ? 127 : (q2 < -127 ? -127 : q2);
    int off = s*4096 + co*64 + ci;
    Bq[off] = (signed char)q1; Bq[36864 + off] = (signed char)q2;
  }
}

// ---- conv1 + LIF: 1024 blocks (img, row-half), 256 thr = 4 waves, 4 blocks/CU.
__global__ __launch_bounds__(256, 4) void conv1_k(
    const float* __restrict__ x, const short* __restrict__ W1F,
    const float* __restrict__ b1, unsigned char* __restrict__ S8)
{
  const int j   = blockIdx.x;
  const int img = j & 511, rh = j >> 9;       // j%8 == img%8 == XCD
  const int tid = threadIdx.x;
  const int w   = tid >> 6;
  const int l   = tid & 63;
  const int lm  = l & 15, lk = l >> 4;

  __shared__ int xt4[1944];                   // xh[3][18][36] + xl (u16 view, 3888 u16)
  __shared__ i32x4 bnc4[4][16][4];            // per-wave spike bounce [16px][64co]
  unsigned short* xs = (unsigned short*)xt4;
  unsigned char*  bnc = (unsigned char*)bnc4;

  for (int i = tid; i < 1944; i += 256) xt4[i] = 0;
  __syncthreads();
  const float* xin = x + (size_t)img * 3072;
  for (int jj = tid; jj < 1728; jj += 256) {  // 3ci x 18 rows x 32 cols
    int ci = jj / 576, rem = jj - ci*576, rl = rem >> 5, c = rem & 31;
    int gr = rh*16 - 1 + rl;
    float f = (gr >= 0 && gr < 32) ? xin[ci*1024 + gr*32 + c] : 0.f;
    __hip_bfloat16 h = __float2bfloat16(f);
    __hip_bfloat16 lo = __float2bfloat16(f - (float)h);
    int idx = ci*648 + rl*36 + (c+1);
    xs[idx] = *(unsigned short*)&h;
    xs[idx + 1944] = *(unsigned short*)&lo;
  }
  __syncthreads();

  bf16x8 Wf[2][4];
  float  b1v[4];
  #pragma unroll
  for (int t2 = 0; t2 < 2; t2++)
    #pragma unroll
    for (int nf = 0; nf < 4; nf++)
      Wf[t2][nf] = *(const bf16x8*)(W1F + t2*2048 + (nf*16+lm)*32 + lk*8);
  #pragma unroll
  for (int nf = 0; nf < 4; nf++) b1v[nf] = b1[nf*16 + lm];

  int off16[8];
  #pragma unroll
  for (int e = 0; e < 8; e++) {
    int k = lk*8 + e;
    if (k < 27) { int s = k/3, ci = k - s*3, dr = s/3, dc = s - dr*3;
                  off16[e] = ci*648 + dr*36 + dc; }
    else off16[e] = 0;
  }

  unsigned char* S8b = S8 + (size_t)img * SZ_IMG;
  for (int fi = 0; fi < 8; fi++) {           // 4 waves x 8 iters x 16 px = 512 px (half img)
    const int pxF = w*8 + fi;
    const int lrow = pxF >> 1, colh = pxF & 1;
    const int base16 = lrow*36 + colh*16 + lm;
    bf16x8 ah, al;
    #pragma unroll
    for (int e = 0; e < 8; e++) {
      int idx = base16 + off16[e];
      ah[e] = (short)xs[idx];
      al[e] = (short)xs[idx + 1944];
    }
    f32x4 acc[4] = {};
    #pragma unroll
    for (int nf = 0; nf < 4; nf++) {
      acc[nf] = __builtin_amdgcn_mfma_f32_16x16x32_bf16(ah, Wf[0][nf], acc[nf], 0,0,0);
      acc[nf] = __builtin_amdgcn_mfma_f32_16x16x32_bf16(al, Wf[0][nf], acc[nf], 0,0,0);
      acc[nf] = __builtin_amdgcn_mfma_f32_16x16x32_bf16(ah, Wf[1][nf], acc[nf], 0,0,0);
      acc[nf] = __builtin_amdgcn_mfma_f32_16x16x32_bf16(al, Wf[1][nf], acc[nf], 0,0,0);
    }
    #pragma unroll
    for (int nf = 0; nf < 4; nf++)
      #pragma unroll
      for (int e4 = 0; e4 < 4; e4++) {
        float v = acc[nf][e4] + b1v[nf];
        bnc[w*1024 + (lk*4+e4)*64 + nf*16 + lm] = (v >= 1.2f) ? 1 : 0;
      }
    const int pxl = l >> 2, coq = l & 3;
    i32x4 sp = *(const i32x4*)(bnc + w*1024 + pxl*64 + coq*16);
    const int gcol = colh*16 + pxl;
    const int grow = rh*16 + lrow;
    const int cq = coq ^ SWZ(gcol + 1);
    *(i32x4*)(S8b + (size_t)(grow*32 + gcol)*64 + cq*16) = sp;
  }
}

// ---- conv2 + LIF + count. 512 blocks (b, 4-row slice), 512 thr = 8 waves, 2 blocks/CU.
// wave = 2 rows x 16 co (cq = wv&3, rp = wv>>2). Bf 72 VGPR + acc 32 -> 4 waves/SIMD.
__global__ __launch_bounds__(512, 4) void conv2_k(
    const unsigned char* __restrict__ S8, const signed char* __restrict__ Bq,
    const float* __restrict__ b2, unsigned char* __restrict__ cnt)
{
  __shared__ __align__(16) unsigned char Abuf[2][13056];   // [buf][6 rows * 2176]
  const int j  = blockIdx.x;
  const int b  = j & 63;                      // b%8 == j%8 == conv1's XCD
  const int rs = j >> 6;                      // 0..7 row-slice (4 rows)
  const int tid = threadIdx.x;
  const int wv = tid >> 6, l = tid & 63;
  const int lm = l & 15, lk = l >> 4;
  const int cq = wv & 3;                      // co quarter: co = cq*16 + lm
  const int rp = wv >> 2;                     // row-pair 0/1

  // persistent B fragments for 16 co: [q][s] = 18 x i32x4 = 72 VGPR
  i32x4 Bf[2][9];
  #pragma unroll
  for (int q = 0; q < 2; q++)
    #pragma unroll
    for (int s = 0; s < 9; s++)
      Bf[q][s] = *(const i32x4*)(Bq + q*36864 + s*4096 + (cq*16+lm)*64 + lk*16);
  const float b2v = b2[cq*16 + lm];

  // zero both buffers (pad cols 0/33 + off-image halo rows stay zero forever)
  {
    i32x4 z = {0,0,0,0};
    i32x4* ap = (i32x4*)Abuf;
    for (int c = tid; c < 1632; c += 512) ap[c] = z;
  }
  __syncthreads();

  // stage t=0 into buf0: waves 0..5 stage LDS row wv (grow = rs*4-1+wv), 128 chunks/row
  if (wv < 6) {
    const int grow = rs*4 - 1 + wv;
    if (grow >= 0 && grow < 32) {
      const unsigned char* src = S8 + (size_t)b*SZ_IMG + grow*2048 + l*16;
      unsigned char* dst = &Abuf[0][wv*2176 + 64];
      gl_lds16(src, dst);
      gl_lds16(src + 1024, dst + 1024);
    }
  }
  __syncthreads();

  unsigned int cntp[4] = {};

  for (int t = 0; t < 8; t++) {
    if (t < 7 && wv < 6) {                    // prefetch t+1 into other buffer
      const int grow = rs*4 - 1 + wv;
      if (grow >= 0 && grow < 32) {
        const unsigned char* src = S8 + (size_t)((t+1)*64 + b)*SZ_IMG + grow*2048 + l*16;
        unsigned char* dst = &Abuf[(t+1) & 1][wv*2176 + 64];
        gl_lds16(src, dst);
        gl_lds16(src + 1024, dst + 1024);
      }
    }

    const unsigned char* ab = Abuf[t & 1];
    i32x4 acc1[4] = {}, acc2[4] = {};
    __builtin_amdgcn_s_setprio(1);
    #pragma unroll
    for (int s = 0; s < 9; s++) {
      const int dr = s/3, dc = s - dr*3;
      #pragma unroll
      for (int a = 0; a < 4; a++) {
        const int lr = rp*2 + (a>>1) + dr;            // 0..5
        const int cp = ((a&1)<<4) + lm + dc;          // 0..33
        i32x4 Af = *(const i32x4*)(ab + lr*2176 + cp*64 + ((lk ^ SWZ(cp)) << 4));
        acc1[a] = __builtin_amdgcn_mfma_i32_16x16x64_i8(Af, Bf[0][s], acc1[a], 0,0,0);
        acc2[a] = __builtin_amdgcn_mfma_i32_16x16x64_i8(Af, Bf[1][s], acc2[a], 0,0,0);
      }
    }
    __builtin_amdgcn_s_setprio(0);

    #pragma unroll
    for (int a = 0; a < 4; a++) {
      unsigned int p = 0;
      #pragma unroll
      for (int e = 0; e < 4; e++) {
        float v = S1Q*(float)acc1[a][e] + S2Q*(float)acc2[a][e] + b2v;
        p |= (v >= 1.2f ? 1u : 0u) << (8*e);
      }
      cntp[a] += p;                           // counts <= 8 per byte, no carry
    }
    __syncthreads();   // drains vmcnt (prefetch landed) + all reads of buf[t&1] done
  }

  // cnt via XOR-skewed LDS bounce (reuses Abuf) -> conflict-free + full 16B lines
  unsigned int* bb = (unsigned int*)Abuf;     // [64 co][32 u32], chunk c' = (u>>2)^(co&7)
  #pragma unroll
  for (int a = 0; a < 4; a++) {
    const int lrow = rp*2 + (a>>1);           // 0..3
    const int u = lrow*8 + (a&1)*4 + lk;      // px-quad index 0..31 (u&3 == lk)
    const int co = cq*16 + lm;
    bb[co*32 + (((u>>2) ^ (co&7))<<2) + (u&3)] = cntp[a];
  }
  __syncthreads();
  {
    const int co = tid >> 3, tc = tid & 7;    // 64 co x 8 chunks of 16B
    i32x4 v = *(const i32x4*)(bb + co*32 + ((tc ^ (co&7)) << 2));
    *(i32x4*)(cnt + (size_t)(b*64 + co)*1024 + rs*128 + tc*16) = v;
  }
}

// ---- FC: 512 blocks = 64 i-slices x 8 b-groups; wave owns 2 b; wfc traffic 21 MB.
__global__ __launch_bounds__(256) void fc_k(
    const unsigned char* __restrict__ cnt, const float* __restrict__ wfc,
    const float* __restrict__ bfc, float* __restrict__ out)
{
  const int ig = blockIdx.x & 63;             // i4 slice of 256 (1024 i)
  const int bg = blockIdx.x >> 6;             // 0..7
  const int tid = threadIdx.x;
  const int w = tid >> 6, l = tid & 63;
  const int b0 = bg*8 + w*2;

  float acc[2][10] = {};
  #pragma unroll
  for (int k = 0; k < 4; k++) {
    const int i4 = ig*256 + k*64 + l;
    float4 wv[10];
    #pragma unroll
    for (int o = 0; o < 10; o++)
      wv[o] = *(const float4*)(wfc + (size_t)o*65536 + (size_t)i4*4);
    #pragma unroll
    for (int bb = 0; bb < 2; bb++) {
      uchar4 cv = *(const uchar4*)(cnt + (size_t)(b0+bb)*65536 + (size_t)i4*4);
      float c0 = cv.x, c1 = cv.y, c2 = cv.z, c3 = cv.w;
      #pragma unroll
      for (int o = 0; o < 10; o++)
        acc[bb][o] += wv[o].x*c0 + wv[o].y*c1 + wv[o].z*c2 + wv[o].w*c3;
    }
  }
  #pragma unroll
  for (int bb = 0; bb < 2; bb++)
    #pragma unroll
    for (int o = 0; o < 10; o++) {
      float v = acc[bb][o];
      for (int off = 32; off > 0; off >>= 1) v += __shfl_down(v, off, 64);
      acc[bb][o] = v;
    }
  if (l == 0) {
    #pragma unroll
    for (int bb = 0; bb < 2; bb++)
      #pragma unroll
      for (int o = 0; o < 10; o++) {
        float v = acc[bb][o];
        if (ig == 0) v += 8.0f * bfc[o];
        atomicAdd(out + (b0+bb)*10 + o, v);
      }
  }
}

extern "C" void kernel_launch(void* const* d_in, const int* in_sizes, int n_in,
                              void* d_out, int out_size, void* d_ws, size_t ws_size,
                              hipStream_t stream)
{
  const float* x   = (const float*)d_in[0];
  const float* w1  = (const float*)d_in[1];
  const float* b1  = (const float*)d_in[2];
  const float* w2  = (const float*)d_in[3];
  const float* b2  = (const float*)d_in[4];
  const float* wfc = (const float*)d_in[5];
  const float* bfc = (const float*)d_in[6];
  float* out = (float*)d_out;

  unsigned char* ws  = (unsigned char*)d_ws;
  unsigned char* S8  = ws + OFF_S8;
  unsigned char* cnt = ws + OFF_CNT;
  short*         W1F = (short*)(ws + OFF_W1F);
  signed char*   Bq  = (signed char*)(ws + OFF_BQ);

  hipMemsetAsync(out, 0, 64*10*sizeof(float), stream);
  kprep<<<144, 256, 0, stream>>>(w1, w2, W1F, Bq);
  conv1_k<<<1024, 256, 0, stream>>>(x, W1F, b1, S8);
  conv2_k<<<512, 512, 0, stream>>>(S8, Bq, b2, cnt);
  fc_k<<<512, 256, 0, stream>>>(cnt, wfc, bfc, out);
}

// Round 9
// 175.307 us; speedup vs baseline: 1.0082x; 1.0082x over previous
//
#include <hip/hip_runtime.h>
#include <hip/hip_bf16.h>

// SNN: conv1(3->64,3x3,p1)+LIF -> conv2(64->64,3x3,p1)+LIF -> FC(65536->10), sum T=8.
// LIF non-recurrent: spike = (pre >= 1.2f).
// conv1: bf16 MFMA 16x16x32, exact 4-term split (xh+xl)(wh+wl), K=27->32 (zero weights).
// conv2: i8 MFMA 16x16x64, 2-term i8 weights (q1+q2; s2=s1/254), spikes exact i8.
// R9: conv2 register budget PINNED via amdgpu_waves_per_eu(4,4) -> cap 128 VGPR, no
//     spill (R8's launch_bounds(512,4) let the backend shrink to 64 VGPR and spill:
//     FETCH 131MB / WRITE 46MB of scratch traffic). Everything else identical to R8.

typedef __attribute__((ext_vector_type(8))) short bf16x8;
typedef __attribute__((ext_vector_type(4))) float f32x4;
typedef __attribute__((ext_vector_type(4))) int   i32x4;

#define S1Q (5.5f/127.0f)       // q1 scale (max|N(0,1)| over 36864 < 5.5 w.p. ~1)
#define S2Q (S1Q/254.0f)        // q2 scale (resid <= s1/2 -> q2 <= 127)

// ws layout
static const size_t SZ_IMG  = 65536;                 // 32*32*64 i8, unpadded spike image
static const size_t OFF_S8  = 0;                     // [512 img] = 33,554,432 B
static const size_t OFF_CNT = 512*SZ_IMG;            // u8 [64b][64co][1024] = 4 MiB
static const size_t OFF_W1F = OFF_CNT + (4u<<20);    // bf16 [2][64co][32k] = 8192 B
static const size_t OFF_BQ  = OFF_W1F + 8192;        // i8 [2q][9s][64co][64ci] = 73,728 B

#define SWZ(cp) (((cp) >> 1) & 3)

__device__ __forceinline__ void gl_lds16(const void* g, void* l) {
  __builtin_amdgcn_global_load_lds(
      (const __attribute__((address_space(1))) unsigned int*)g,
      (__attribute__((address_space(3))) unsigned int*)l, 16, 0, 0);
}

// ---- prep: conv1 weights bf16 hi/lo; conv2 weights 2-term i8
__global__ __launch_bounds__(256) void kprep(
    const float* __restrict__ w1, const float* __restrict__ w2,
    short* __restrict__ W1F, signed char* __restrict__ Bq)
{
  int i = blockIdx.x*256 + threadIdx.x;
  if (i < 4096) {                       // W1F[t2][co][k]
    int t2 = i >> 11, r = i & 2047, co = r >> 5, k = r & 31;
    short out = 0;
    if (k < 27) {
      int s = k/3, ci = k - s*3;
      float w = w1[co*27 + ci*9 + s];
      __hip_bfloat16 h = __float2bfloat16(w);
      if (t2 == 0) out = *(short*)&h;
      else { __hip_bfloat16 lo = __float2bfloat16(w - (float)h); out = *(short*)&lo; }
    }
    W1F[i] = out;
  }
  if (i < 36864) {                      // Bq[q][s][co][ci]
    int co = i/576, rem = i - co*576, ci = rem/9, s = rem - ci*9;
    float w = w2[i];
    int q1 = (int)roundf(w * (1.0f/S1Q)); q1 = q1 > 127 ? 127 : (q1 < -127 ? -127 : q1);
    float r1 = w - S1Q*(float)q1;
    int q2 = (int)roundf(r1 * (1.0f/S2Q)); q2 = q2 > 127 ? 127 : (q2 < -127 ? -127 : q2);
    int off = s*4096 + co*64 + ci;
    Bq[off] = (signed char)q1; Bq[36864 + off] = (signed char)q2;
  }
}

// ---- conv1 + LIF: 1024 blocks (img, row-half), 256 thr = 4 waves, 4 blocks/CU.
__global__ __launch_bounds__(256, 4) void conv1_k(
    const float* __restrict__ x, const short* __restrict__ W1F,
    const float* __restrict__ b1, unsigned char* __restrict__ S8)
{
  const int j   = blockIdx.x;
  const int img = j & 511, rh = j >> 9;       // j%8 == img%8 == XCD
  const int tid = threadIdx.x;
  const int w   = tid >> 6;
  const int l   = tid & 63;
  const int lm  = l & 15, lk = l >> 4;

  __shared__ int xt4[1944];                   // xh[3][18][36] + xl (u16 view, 3888 u16)
  __shared__ i32x4 bnc4[4][16][4];            // per-wave spike bounce [16px][64co]
  unsigned short* xs = (unsigned short*)xt4;
  unsigned char*  bnc = (unsigned char*)bnc4;

  for (int i = tid; i < 1944; i += 256) xt4[i] = 0;
  __syncthreads();
  const float* xin = x + (size_t)img * 3072;
  for (int jj = tid; jj < 1728; jj += 256) {  // 3ci x 18 rows x 32 cols
    int ci = jj / 576, rem = jj - ci*576, rl = rem >> 5, c = rem & 31;
    int gr = rh*16 - 1 + rl;
    float f = (gr >= 0 && gr < 32) ? xin[ci*1024 + gr*32 + c] : 0.f;
    __hip_bfloat16 h = __float2bfloat16(f);
    __hip_bfloat16 lo = __float2bfloat16(f - (float)h);
    int idx = ci*648 + rl*36 + (c+1);
    xs[idx] = *(unsigned short*)&h;
    xs[idx + 1944] = *(unsigned short*)&lo;
  }
  __syncthreads();

  bf16x8 Wf[2][4];
  float  b1v[4];
  #pragma unroll
  for (int t2 = 0; t2 < 2; t2++)
    #pragma unroll
    for (int nf = 0; nf < 4; nf++)
      Wf[t2][nf] = *(const bf16x8*)(W1F + t2*2048 + (nf*16+lm)*32 + lk*8);
  #pragma unroll
  for (int nf = 0; nf < 4; nf++) b1v[nf] = b1[nf*16 + lm];

  int off16[8];
  #pragma unroll
  for (int e = 0; e < 8; e++) {
    int k = lk*8 + e;
    if (k < 27) { int s = k/3, ci = k - s*3, dr = s/3, dc = s - dr*3;
                  off16[e] = ci*648 + dr*36 + dc; }
    else off16[e] = 0;
  }

  unsigned char* S8b = S8 + (size_t)img * SZ_IMG;
  for (int fi = 0; fi < 8; fi++) {           // 4 waves x 8 iters x 16 px = 512 px (half img)
    const int pxF = w*8 + fi;
    const int lrow = pxF >> 1, colh = pxF & 1;
    const int base16 = lrow*36 + colh*16 + lm;
    bf16x8 ah, al;
    #pragma unroll
    for (int e = 0; e < 8; e++) {
      int idx = base16 + off16[e];
      ah[e] = (short)xs[idx];
      al[e] = (short)xs[idx + 1944];
    }
    f32x4 acc[4] = {};
    #pragma unroll
    for (int nf = 0; nf < 4; nf++) {
      acc[nf] = __builtin_amdgcn_mfma_f32_16x16x32_bf16(ah, Wf[0][nf], acc[nf], 0,0,0);
      acc[nf] = __builtin_amdgcn_mfma_f32_16x16x32_bf16(al, Wf[0][nf], acc[nf], 0,0,0);
      acc[nf] = __builtin_amdgcn_mfma_f32_16x16x32_bf16(ah, Wf[1][nf], acc[nf], 0,0,0);
      acc[nf] = __builtin_amdgcn_mfma_f32_16x16x32_bf16(al, Wf[1][nf], acc[nf], 0,0,0);
    }
    #pragma unroll
    for (int nf = 0; nf < 4; nf++)
      #pragma unroll
      for (int e4 = 0; e4 < 4; e4++) {
        float v = acc[nf][e4] + b1v[nf];
        bnc[w*1024 + (lk*4+e4)*64 + nf*16 + lm] = (v >= 1.2f) ? 1 : 0;
      }
    const int pxl = l >> 2, coq = l & 3;
    i32x4 sp = *(const i32x4*)(bnc + w*1024 + pxl*64 + coq*16);
    const int gcol = colh*16 + pxl;
    const int grow = rh*16 + lrow;
    const int cq = coq ^ SWZ(gcol + 1);
    *(i32x4*)(S8b + (size_t)(grow*32 + gcol)*64 + cq*16) = sp;
  }
}

// ---- conv2 + LIF + count. 512 blocks (b, 4-row slice), 512 thr = 8 waves, 2 blocks/CU.
// wave = 2 rows x 16 co (cq = wv&3, rp = wv>>2). Bf 72 VGPR + acc 32; waves_per_eu
// pinned 4,4 -> VGPR cap 128, no spill (R8 lesson).
__global__ __launch_bounds__(512)
__attribute__((amdgpu_waves_per_eu(4, 4)))
void conv2_k(
    const unsigned char* __restrict__ S8, const signed char* __restrict__ Bq,
    const float* __restrict__ b2, unsigned char* __restrict__ cnt)
{
  __shared__ __align__(16) unsigned char Abuf[2][13056];   // [buf][6 rows * 2176]
  const int j  = blockIdx.x;
  const int b  = j & 63;                      // b%8 == j%8 == conv1's XCD
  const int rs = j >> 6;                      // 0..7 row-slice (4 rows)
  const int tid = threadIdx.x;
  const int wv = tid >> 6, l = tid & 63;
  const int lm = l & 15, lk = l >> 4;
  const int cq = wv & 3;                      // co quarter: co = cq*16 + lm
  const int rp = wv >> 2;                     // row-pair 0/1

  // persistent B fragments for 16 co: [q][s] = 18 x i32x4 = 72 VGPR
  i32x4 Bf[2][9];
  #pragma unroll
  for (int q = 0; q < 2; q++)
    #pragma unroll
    for (int s = 0; s < 9; s++)
      Bf[q][s] = *(const i32x4*)(Bq + q*36864 + s*4096 + (cq*16+lm)*64 + lk*16);
  const float b2v = b2[cq*16 + lm];

  // zero both buffers (pad cols 0/33 + off-image halo rows stay zero forever)
  {
    i32x4 z = {0,0,0,0};
    i32x4* ap = (i32x4*)Abuf;
    for (int c = tid; c < 1632; c += 512) ap[c] = z;
  }
  __syncthreads();

  // stage t=0 into buf0: waves 0..5 stage LDS row wv (grow = rs*4-1+wv), 128 chunks/row
  if (wv < 6) {
    const int grow = rs*4 - 1 + wv;
    if (grow >= 0 && grow < 32) {
      const unsigned char* src = S8 + (size_t)b*SZ_IMG + grow*2048 + l*16;
      unsigned char* dst = &Abuf[0][wv*2176 + 64];
      gl_lds16(src, dst);
      gl_lds16(src + 1024, dst + 1024);
    }
  }
  __syncthreads();

  unsigned int cntp[4] = {};

  for (int t = 0; t < 8; t++) {
    if (t < 7 && wv < 6) {                    // prefetch t+1 into other buffer
      const int grow = rs*4 - 1 + wv;
      if (grow >= 0 && grow < 32) {
        const unsigned char* src = S8 + (size_t)((t+1)*64 + b)*SZ_IMG + grow*2048 + l*16;
        unsigned char* dst = &Abuf[(t+1) & 1][wv*2176 + 64];
        gl_lds16(src, dst);
        gl_lds16(src + 1024, dst + 1024);
      }
    }

    const unsigned char* ab = Abuf[t & 1];
    i32x4 acc1[4] = {}, acc2[4] = {};
    __builtin_amdgcn_s_setprio(1);
    #pragma unroll
    for (int s = 0; s < 9; s++) {
      const int dr = s/3, dc = s - dr*3;
      #pragma unroll
      for (int a = 0; a < 4; a++) {
        const int lr = rp*2 + (a>>1) + dr;            // 0..5
        const int cp = ((a&1)<<4) + lm + dc;          // 0..33
        i32x4 Af = *(const i32x4*)(ab + lr*2176 + cp*64 + ((lk ^ SWZ(cp)) << 4));
        acc1[a] = __builtin_amdgcn_mfma_i32_16x16x64_i8(Af, Bf[0][s], acc1[a], 0,0,0);
        acc2[a] = __builtin_amdgcn_mfma_i32_16x16x64_i8(Af, Bf[1][s], acc2[a], 0,0,0);
      }
    }
    __builtin_amdgcn_s_setprio(0);

    #pragma unroll
    for (int a = 0; a < 4; a++) {
      unsigned int p = 0;
      #pragma unroll
      for (int e = 0; e < 4; e++) {
        float v = S1Q*(float)acc1[a][e] + S2Q*(float)acc2[a][e] + b2v;
        p |= (v >= 1.2f ? 1u : 0u) << (8*e);
      }
      cntp[a] += p;                           // counts <= 8 per byte, no carry
    }
    __syncthreads();   // drains vmcnt (prefetch landed) + all reads of buf[t&1] done
  }

  // cnt via XOR-skewed LDS bounce (reuses Abuf) -> conflict-free + full 16B lines
  unsigned int* bb = (unsigned int*)Abuf;     // [64 co][32 u32], chunk c' = (u>>2)^(co&7)
  #pragma unroll
  for (int a = 0; a < 4; a++) {
    const int lrow = rp*2 + (a>>1);           // 0..3
    const int u = lrow*8 + (a&1)*4 + lk;      // px-quad index 0..31 (u&3 == lk)
    const int co = cq*16 + lm;
    bb[co*32 + (((u>>2) ^ (co&7))<<2) + (u&3)] = cntp[a];
  }
  __syncthreads();
  {
    const int co = tid >> 3, tc = tid & 7;    // 64 co x 8 chunks of 16B
    i32x4 v = *(const i32x4*)(bb + co*32 + ((tc ^ (co&7)) << 2));
    *(i32x4*)(cnt + (size_t)(b*64 + co)*1024 + rs*128 + tc*16) = v;
  }
}

// ---- FC: 512 blocks = 64 i-slices x 8 b-groups; wave owns 2 b; wfc traffic 21 MB.
__global__ __launch_bounds__(256) void fc_k(
    const unsigned char* __restrict__ cnt, const float* __restrict__ wfc,
    const float* __restrict__ bfc, float* __restrict__ out)
{
  const int ig = blockIdx.x & 63;             // i4 slice of 256 (1024 i)
  const int bg = blockIdx.x >> 6;             // 0..7
  const int tid = threadIdx.x;
  const int w = tid >> 6, l = tid & 63;
  const int b0 = bg*8 + w*2;

  float acc[2][10] = {};
  #pragma unroll
  for (int k = 0; k < 4; k++) {
    const int i4 = ig*256 + k*64 + l;
    float4 wv[10];
    #pragma unroll
    for (int o = 0; o < 10; o++)
      wv[o] = *(const float4*)(wfc + (size_t)o*65536 + (size_t)i4*4);
    #pragma unroll
    for (int bb = 0; bb < 2; bb++) {
      uchar4 cv = *(const uchar4*)(cnt + (size_t)(b0+bb)*65536 + (size_t)i4*4);
      float c0 = cv.x, c1 = cv.y, c2 = cv.z, c3 = cv.w;
      #pragma unroll
      for (int o = 0; o < 10; o++)
        acc[bb][o] += wv[o].x*c0 + wv[o].y*c1 + wv[o].z*c2 + wv[o].w*c3;
    }
  }
  #pragma unroll
  for (int bb = 0; bb < 2; bb++)
    #pragma unroll
    for (int o = 0; o < 10; o++) {
      float v = acc[bb][o];
      for (int off = 32; off > 0; off >>= 1) v += __shfl_down(v, off, 64);
      acc[bb][o] = v;
    }
  if (l == 0) {
    #pragma unroll
    for (int bb = 0; bb < 2; bb++)
      #pragma unroll
      for (int o = 0; o < 10; o++) {
        float v = acc[bb][o];
        if (ig == 0) v += 8.0f * bfc[o];
        atomicAdd(out + (b0+bb)*10 + o, v);
      }
  }
}

extern "C" void kernel_launch(void* const* d_in, const int* in_sizes, int n_in,
                              void* d_out, int out_size, void* d_ws, size_t ws_size,
                              hipStream_t stream)
{
  const float* x   = (const float*)d_in[0];
  const float* w1  = (const float*)d_in[1];
  const float* b1  = (const float*)d_in[2];
  const float* w2  = (const float*)d_in[3];
  const float* b2  = (const float*)d_in[4];
  const float* wfc = (const float*)d_in[5];
  const float* bfc = (const float*)d_in[6];
  float* out = (float*)d_out;

  unsigned char* ws  = (unsigned char*)d_ws;
  unsigned char* S8  = ws + OFF_S8;
  unsigned char* cnt = ws + OFF_CNT;
  short*         W1F = (short*)(ws + OFF_W1F);
  signed char*   Bq  = (signed char*)(ws + OFF_BQ);

  hipMemsetAsync(out, 0, 64*10*sizeof(float), stream);
  kprep<<<144, 256, 0, stream>>>(w1, w2, W1F, Bq);
  conv1_k<<<1024, 256, 0, stream>>>(x, W1F, b1, S8);
  conv2_k<<<512, 512, 0, stream>>>(S8, Bq, b2, cnt);
  fc_k<<<512, 256, 0, stream>>>(cnt, wfc, bfc, out);
}

// Round 10
// 146.084 us; speedup vs baseline: 1.2098x; 1.2000x over previous
//
#include <hip/hip_runtime.h>
#include <hip/hip_bf16.h>

// SNN: conv1(3->64,3x3,p1)+LIF -> conv2(64->64,3x3,p1)+LIF -> FC(65536->10), sum T=8.
// LIF non-recurrent: spike = (pre >= 1.2f).
// conv1: bf16 MFMA 16x16x32, exact 4-term split (xh+xl)(wh+wl), K=27->32 (zero weights).
// conv2: i8 MFMA 16x16x64, 2-term i8 weights (q1+q2; s2=s1/254), spikes exact i8.
// R10: conv2 B streamed from LDS (36KB/co-half) instead of 72 persistent VGPRs ->
//      live regs ~70, no spill at ANY allocator choice (R8/R9: 4-wave requests caused
//      64-VGPR clamp + spill, FETCH 130MB). LDS 80.4KB dynamic -> 2 blocks/CU =
//      4 waves/SIMD. Wave = 2 rows x 16 co x both q. kprep absorbs out-zero.

typedef __attribute__((ext_vector_type(8))) short bf16x8;
typedef __attribute__((ext_vector_type(4))) float f32x4;
typedef __attribute__((ext_vector_type(4))) int   i32x4;

#define S1Q (5.5f/127.0f)       // q1 scale (max|N(0,1)| over 36864 < 5.5 w.p. ~1)
#define S2Q (S1Q/254.0f)        // q2 scale (resid <= s1/2 -> q2 <= 127)

// ws layout
static const size_t SZ_IMG  = 65536;                 // 32*32*64 i8, unpadded spike image
static const size_t OFF_S8  = 0;                     // [512 img] = 33,554,432 B
static const size_t OFF_CNT = 512*SZ_IMG;            // u8 [64b][64co][1024] = 4 MiB
static const size_t OFF_W1F = OFF_CNT + (4u<<20);    // bf16 [2][64co][32k] = 8192 B
static const size_t OFF_BQ  = OFF_W1F + 8192;        // i8 [2q][9s][64co][64ci] = 73,728 B

#define SWZ(cp) (((cp) >> 1) & 3)

__device__ __forceinline__ void gl_lds16(const void* g, void* l) {
  __builtin_amdgcn_global_load_lds(
      (const __attribute__((address_space(1))) unsigned int*)g,
      (__attribute__((address_space(3))) unsigned int*)l, 16, 0, 0);
}

// ---- prep: conv1 weights bf16 hi/lo; conv2 weights 2-term i8; zero `out`
__global__ __launch_bounds__(256) void kprep(
    const float* __restrict__ w1, const float* __restrict__ w2,
    short* __restrict__ W1F, signed char* __restrict__ Bq, float* __restrict__ out)
{
  int i = blockIdx.x*256 + threadIdx.x;
  if (i < 640) out[i] = 0.f;            // 64b x 10 outputs (fc accumulates atomically)
  if (i < 4096) {                       // W1F[t2][co][k]
    int t2 = i >> 11, r = i & 2047, co = r >> 5, k = r & 31;
    short o = 0;
    if (k < 27) {
      int s = k/3, ci = k - s*3;
      float w = w1[co*27 + ci*9 + s];
      __hip_bfloat16 h = __float2bfloat16(w);
      if (t2 == 0) o = *(short*)&h;
      else { __hip_bfloat16 lo = __float2bfloat16(w - (float)h); o = *(short*)&lo; }
    }
    W1F[i] = o;
  }
  if (i < 36864) {                      // Bq[q][s][co][ci]
    int co = i/576, rem = i - co*576, ci = rem/9, s = rem - ci*9;
    float w = w2[i];
    int q1 = (int)roundf(w * (1.0f/S1Q)); q1 = q1 > 127 ? 127 : (q1 < -127 ? -127 : q1);
    float r1 = w - S1Q*(float)q1;
    int q2 = (int)roundf(r1 * (1.0f/S2Q)); q2 = q2 > 127 ? 127 : (q2 < -127 ? -127 : q2);
    int off = s*4096 + co*64 + ci;
    Bq[off] = (signed char)q1; Bq[36864 + off] = (signed char)q2;
  }
}

// ---- conv1 + LIF: 1024 blocks (img, row-half), 256 thr = 4 waves, 4 blocks/CU.
__global__ __launch_bounds__(256, 4) void conv1_k(
    const float* __restrict__ x, const short* __restrict__ W1F,
    const float* __restrict__ b1, unsigned char* __restrict__ S8)
{
  const int j   = blockIdx.x;
  const int img = j & 511, rh = j >> 9;       // j%8 == img%8 == XCD
  const int tid = threadIdx.x;
  const int w   = tid >> 6;
  const int l   = tid & 63;
  const int lm  = l & 15, lk = l >> 4;

  __shared__ int xt4[1944];                   // xh[3][18][36] + xl (u16 view, 3888 u16)
  __shared__ i32x4 bnc4[4][16][4];            // per-wave spike bounce [16px][64co]
  unsigned short* xs = (unsigned short*)xt4;
  unsigned char*  bnc = (unsigned char*)bnc4;

  for (int i = tid; i < 1944; i += 256) xt4[i] = 0;
  __syncthreads();
  const float* xin = x + (size_t)img * 3072;
  for (int jj = tid; jj < 1728; jj += 256) {  // 3ci x 18 rows x 32 cols
    int ci = jj / 576, rem = jj - ci*576, rl = rem >> 5, c = rem & 31;
    int gr = rh*16 - 1 + rl;
    float f = (gr >= 0 && gr < 32) ? xin[ci*1024 + gr*32 + c] : 0.f;
    __hip_bfloat16 h = __float2bfloat16(f);
    __hip_bfloat16 lo = __float2bfloat16(f - (float)h);
    int idx = ci*648 + rl*36 + (c+1);
    xs[idx] = *(unsigned short*)&h;
    xs[idx + 1944] = *(unsigned short*)&lo;
  }
  __syncthreads();

  bf16x8 Wf[2][4];
  float  b1v[4];
  #pragma unroll
  for (int t2 = 0; t2 < 2; t2++)
    #pragma unroll
    for (int nf = 0; nf < 4; nf++)
      Wf[t2][nf] = *(const bf16x8*)(W1F + t2*2048 + (nf*16+lm)*32 + lk*8);
  #pragma unroll
  for (int nf = 0; nf < 4; nf++) b1v[nf] = b1[nf*16 + lm];

  int off16[8];
  #pragma unroll
  for (int e = 0; e < 8; e++) {
    int k = lk*8 + e;
    if (k < 27) { int s = k/3, ci = k - s*3, dr = s/3, dc = s - dr*3;
                  off16[e] = ci*648 + dr*36 + dc; }
    else off16[e] = 0;
  }

  unsigned char* S8b = S8 + (size_t)img * SZ_IMG;
  for (int fi = 0; fi < 8; fi++) {           // 4 waves x 8 iters x 16 px = 512 px (half img)
    const int pxF = w*8 + fi;
    const int lrow = pxF >> 1, colh = pxF & 1;
    const int base16 = lrow*36 + colh*16 + lm;
    bf16x8 ah, al;
    #pragma unroll
    for (int e = 0; e < 8; e++) {
      int idx = base16 + off16[e];
      ah[e] = (short)xs[idx];
      al[e] = (short)xs[idx + 1944];
    }
    f32x4 acc[4] = {};
    #pragma unroll
    for (int nf = 0; nf < 4; nf++) {
      acc[nf] = __builtin_amdgcn_mfma_f32_16x16x32_bf16(ah, Wf[0][nf], acc[nf], 0,0,0);
      acc[nf] = __builtin_amdgcn_mfma_f32_16x16x32_bf16(al, Wf[0][nf], acc[nf], 0,0,0);
      acc[nf] = __builtin_amdgcn_mfma_f32_16x16x32_bf16(ah, Wf[1][nf], acc[nf], 0,0,0);
      acc[nf] = __builtin_amdgcn_mfma_f32_16x16x32_bf16(al, Wf[1][nf], acc[nf], 0,0,0);
    }
    #pragma unroll
    for (int nf = 0; nf < 4; nf++)
      #pragma unroll
      for (int e4 = 0; e4 < 4; e4++) {
        float v = acc[nf][e4] + b1v[nf];
        bnc[w*1024 + (lk*4+e4)*64 + nf*16 + lm] = (v >= 1.2f) ? 1 : 0;
      }
    const int pxl = l >> 2, coq = l & 3;
    i32x4 sp = *(const i32x4*)(bnc + w*1024 + pxl*64 + coq*16);
    const int gcol = colh*16 + pxl;
    const int grow = rh*16 + lrow;
    const int cq = coq ^ SWZ(gcol + 1);
    *(i32x4*)(S8b + (size_t)(grow*32 + gcol)*64 + cq*16) = sp;
  }
}

// ---- conv2 + LIF + count. 512 blocks (b, 8-row slice, co-half), 512 thr = 8 waves.
// wave = 2 rows x 16 co x both q (rp = wv>>1, cq = wv&1). B streamed from LDS.
// Dynamic LDS: Abuf dbuf [2][10*2176]=43520 + Blds [2q][9s][32co][64ci]=36864 -> 80384 B
// -> 2 blocks/CU = 4 waves/SIMD. Live regs ~70: no spill regardless of allocator.
__global__ __launch_bounds__(512, 2) void conv2_k(
    const unsigned char* __restrict__ S8, const signed char* __restrict__ Bq,
    const float* __restrict__ b2, unsigned char* __restrict__ cnt)
{
  extern __shared__ __align__(16) unsigned char lds[];
  unsigned char* Abuf = lds;                  // [2][21760]
  unsigned char* Blds = lds + 43520;          // [q][s][colocal][ci]

  const int j  = blockIdx.x;
  const int b  = j & 63;                      // b%8 == j%8 == conv1's XCD
  const int rs = (j >> 6) & 3;                // 8-row slice
  const int ch = j >> 8;                      // co half
  const int tid = threadIdx.x;
  const int wv = tid >> 6, l = tid & 63;
  const int lm = l & 15, lk = l >> 4;
  const int rp = wv >> 1;                     // row-pair 0..3
  const int cq = wv & 1;                      // co quarter within half
  const int colocal = cq*16 + lm;

  const float b2v = b2[ch*32 + colocal];

  // zero Abuf (pad cols + halo rows stay zero; interior re-staged per t)
  {
    i32x4 z = {0,0,0,0};
    i32x4* ap = (i32x4*)Abuf;
    for (int c = tid; c < 2720; c += 512) ap[c] = z;
  }
  __syncthreads();

  // stage B half (2304 chunks) + A tile t=0 (1280 chunks, rows rs*8-1 .. rs*8+8)
  {
    const signed char* Bsrc = Bq;
    #pragma unroll
    for (int it = 0; it < 5; it++) {
      const int c = it*512 + tid;
      if (c < 2304) {
        const int q = c / 1152, r = c - q*1152, s = r >> 7, r2 = r & 127;
        const int col = r2 >> 2, cic = r2 & 3;
        gl_lds16(Bsrc + q*36864 + s*4096 + (ch*32+col)*64 + cic*16, Blds + c*16);
      }
    }
    const unsigned char* Simg = S8 + (size_t)b*SZ_IMG;
    #pragma unroll
    for (int it = 0; it < 3; it++) {
      const int c = it*512 + tid;
      if (c < 1280) {
        const int row = c >> 7, grow = rs*8 - 1 + row;
        if (grow >= 0 && grow < 32)
          gl_lds16(Simg + grow*2048 + (c&127)*16, Abuf + row*2176 + 64 + (c&127)*16);
      }
    }
  }
  __syncthreads();

  unsigned int cntp[4] = {};

  for (int t = 0; t < 8; t++) {
    if (t < 7) {                              // prefetch t+1 into other buffer
      const unsigned char* Simg = S8 + (size_t)((t+1)*64 + b)*SZ_IMG;
      unsigned char* bufn = Abuf + ((t+1) & 1)*21760;
      #pragma unroll
      for (int it = 0; it < 3; it++) {
        const int c = it*512 + tid;
        if (c < 1280) {
          const int row = c >> 7, grow = rs*8 - 1 + row;
          if (grow >= 0 && grow < 32)
            gl_lds16(Simg + grow*2048 + (c&127)*16, bufn + row*2176 + 64 + (c&127)*16);
        }
      }
    }

    const unsigned char* ab = Abuf + (t & 1)*21760;
    i32x4 acc1[4] = {}, acc2[4] = {};
    __builtin_amdgcn_s_setprio(1);
    #pragma unroll
    for (int s = 0; s < 9; s++) {
      const int dr = s/3, dc = s - dr*3;
      i32x4 Bf1 = *(const i32x4*)(Blds + s*2048 + colocal*64 + lk*16);
      i32x4 Bf2 = *(const i32x4*)(Blds + 18432 + s*2048 + colocal*64 + lk*16);
      #pragma unroll
      for (int a = 0; a < 4; a++) {
        const int lr = rp*2 + (a>>1) + dr;            // 0..9
        const int cp = ((a&1)<<4) + lm + dc;          // 0..33
        i32x4 Af = *(const i32x4*)(ab + lr*2176 + cp*64 + ((lk ^ SWZ(cp)) << 4));
        acc1[a] = __builtin_amdgcn_mfma_i32_16x16x64_i8(Af, Bf1, acc1[a], 0,0,0);
        acc2[a] = __builtin_amdgcn_mfma_i32_16x16x64_i8(Af, Bf2, acc2[a], 0,0,0);
      }
    }
    __builtin_amdgcn_s_setprio(0);

    #pragma unroll
    for (int a = 0; a < 4; a++) {
      unsigned int p = 0;
      #pragma unroll
      for (int e = 0; e < 4; e++) {
        float v = S1Q*(float)acc1[a][e] + S2Q*(float)acc2[a][e] + b2v;
        p |= (v >= 1.2f ? 1u : 0u) << (8*e);
      }
      cntp[a] += p;                           // counts <= 8 per byte, no carry
    }
    __syncthreads();   // drains vmcnt (prefetch landed) + all reads of buf[t&1] done
  }

  // cnt via XOR-skewed LDS bounce (reuses Abuf buf0) -> 2-way-max conflicts, 16B lines
  unsigned int* bb = (unsigned int*)Abuf;     // [32 colocal][64 u32]
  #pragma unroll
  for (int a = 0; a < 4; a++) {
    const int lrow = rp*2 + (a>>1);           // 0..7
    const int u = lrow*8 + (a&1)*4 + lk;      // px-quad 0..63 (u&3 == lk)
    bb[colocal*64 + (((u>>2) ^ (colocal & 15)) << 2) + (u&3)] = cntp[a];
  }
  __syncthreads();
  {
    const int co = tid >> 4, tc = tid & 15;   // 32 colocal x 16 slots of 16B
    i32x4 v = *(const i32x4*)(bb + co*64 + (tc << 2));
    const int g = tc ^ (co & 15);             // unskew: slot tc holds px-group g
    *(i32x4*)(cnt + (size_t)(b*64 + ch*32 + co)*1024 + rs*256 + g*16) = v;
  }
}

// ---- FC: 512 blocks = 64 i-slices x 8 b-groups; wave owns 2 b; wfc traffic 21 MB.
__global__ __launch_bounds__(256) void fc_k(
    const unsigned char* __restrict__ cnt, const float* __restrict__ wfc,
    const float* __restrict__ bfc, float* __restrict__ out)
{
  const int ig = blockIdx.x & 63;             // i4 slice of 256 (1024 i)
  const int bg = blockIdx.x >> 6;             // 0..7
  const int tid = threadIdx.x;
  const int w = tid >> 6, l = tid & 63;
  const int b0 = bg*8 + w*2;

  float acc[2][10] = {};
  #pragma unroll
  for (int k = 0; k < 4; k++) {
    const int i4 = ig*256 + k*64 + l;
    float4 wv[10];
    #pragma unroll
    for (int o = 0; o < 10; o++)
      wv[o] = *(const float4*)(wfc + (size_t)o*65536 + (size_t)i4*4);
    #pragma unroll
    for (int bb = 0; bb < 2; bb++) {
      uchar4 cv = *(const uchar4*)(cnt + (size_t)(b0+bb)*65536 + (size_t)i4*4);
      float c0 = cv.x, c1 = cv.y, c2 = cv.z, c3 = cv.w;
      #pragma unroll
      for (int o = 0; o < 10; o++)
        acc[bb][o] += wv[o].x*c0 + wv[o].y*c1 + wv[o].z*c2 + wv[o].w*c3;
    }
  }
  #pragma unroll
  for (int bb = 0; bb < 2; bb++)
    #pragma unroll
    for (int o = 0; o < 10; o++) {
      float v = acc[bb][o];
      for (int off = 32; off > 0; off >>= 1) v += __shfl_down(v, off, 64);
      acc[bb][o] = v;
    }
  if (l == 0) {
    #pragma unroll
    for (int bb = 0; bb < 2; bb++)
      #pragma unroll
      for (int o = 0; o < 10; o++) {
        float v = acc[bb][o];
        if (ig == 0) v += 8.0f * bfc[o];
        atomicAdd(out + (b0+bb)*10 + o, v);
      }
  }
}

extern "C" void kernel_launch(void* const* d_in, const int* in_sizes, int n_in,
                              void* d_out, int out_size, void* d_ws, size_t ws_size,
                              hipStream_t stream)
{
  const float* x   = (const float*)d_in[0];
  const float* w1  = (const float*)d_in[1];
  const float* b1  = (const float*)d_in[2];
  const float* w2  = (const float*)d_in[3];
  const float* b2  = (const float*)d_in[4];
  const float* wfc = (const float*)d_in[5];
  const float* bfc = (const float*)d_in[6];
  float* out = (float*)d_out;

  unsigned char* ws  = (unsigned char*)d_ws;
  unsigned char* S8  = ws + OFF_S8;
  unsigned char* cnt = ws + OFF_CNT;
  short*         W1F = (short*)(ws + OFF_W1F);
  signed char*   Bq  = (signed char*)(ws + OFF_BQ);

  kprep<<<144, 256, 0, stream>>>(w1, w2, W1F, Bq, out);
  conv1_k<<<1024, 256, 0, stream>>>(x, W1F, b1, S8);
  conv2_k<<<512, 512, 80384, stream>>>(S8, Bq, b2, cnt);
  fc_k<<<512, 256, 0, stream>>>(cnt, wfc, bfc, out);
}

// Round 11
// 136.229 us; speedup vs baseline: 1.2974x; 1.0723x over previous
//
#include <hip/hip_runtime.h>
#include <hip/hip_bf16.h>

// SNN: conv1(3->64,3x3,p1)+LIF -> conv2(64->64,3x3,p1)+LIF -> FC(65536->10), sum T=8.
// LIF non-recurrent: spike = (pre >= 1.2f).
// conv1: bf16 MFMA 16x16x32, exact 4-term split (xh+xl)(wh+wl), K=27->32 (zero weights).
// conv2: i8 MFMA 16x16x64, 2-term i8 weights (q1+q2; s2=s1/254), spikes exact i8.
// R11: FC fused into conv2 epilogue (cnt never leaves LDS; fc_k + 8MB cnt traffic gone);
//      kprep = Bq + out-bias only; conv1 self-computes weight fragments from w1.
//      3 launches total. conv2 geometry unchanged from R10 (B streamed from LDS,
//      80.4KB dynamic LDS, 2 blocks/CU = 4 waves/SIMD, no spill).

typedef __attribute__((ext_vector_type(8))) short bf16x8;
typedef __attribute__((ext_vector_type(4))) float f32x4;
typedef __attribute__((ext_vector_type(4))) int   i32x4;

#define S1Q (5.5f/127.0f)       // q1 scale (max|N(0,1)| over 36864 < 5.5 w.p. ~1)
#define S2Q (S1Q/254.0f)        // q2 scale (resid <= s1/2 -> q2 <= 127)

// ws layout
static const size_t SZ_IMG  = 65536;                 // 32*32*64 i8, unpadded spike image
static const size_t OFF_S8  = 0;                     // [512 img] = 33,554,432 B
static const size_t OFF_BQ  = 512*SZ_IMG;            // i8 [2q][9s][64co][64ci] = 73,728 B

#define SWZ(cp) (((cp) >> 1) & 3)

__device__ __forceinline__ void gl_lds16(const void* g, void* l) {
  __builtin_amdgcn_global_load_lds(
      (const __attribute__((address_space(1))) unsigned int*)g,
      (__attribute__((address_space(3))) unsigned int*)l, 16, 0, 0);
}

// ---- prep: conv2 weights 2-term i8; preload out with 8*bfc (out poisoned each iter)
__global__ __launch_bounds__(256) void kprep(
    const float* __restrict__ w2, const float* __restrict__ bfc,
    signed char* __restrict__ Bq, float* __restrict__ out)
{
  int i = blockIdx.x*256 + threadIdx.x;
  if (i < 640) out[i] = 8.0f * bfc[i % 10];
  if (i < 36864) {                      // Bq[q][s][co][ci]
    int co = i/576, rem = i - co*576, ci = rem/9, s = rem - ci*9;
    float w = w2[i];
    int q1 = (int)roundf(w * (1.0f/S1Q)); q1 = q1 > 127 ? 127 : (q1 < -127 ? -127 : q1);
    float r1 = w - S1Q*(float)q1;
    int q2 = (int)roundf(r1 * (1.0f/S2Q)); q2 = q2 > 127 ? 127 : (q2 < -127 ? -127 : q2);
    int off = s*4096 + co*64 + ci;
    Bq[off] = (signed char)q1; Bq[36864 + off] = (signed char)q2;
  }
}

// ---- conv1 + LIF: 1024 blocks (img, row-half), 256 thr = 4 waves, 4 blocks/CU.
// Weight fragments computed in-block from w1 (hi/lo bf16 split), K=27 padded to 32.
__global__ __launch_bounds__(256, 4) void conv1_k(
    const float* __restrict__ x, const float* __restrict__ w1,
    const float* __restrict__ b1, unsigned char* __restrict__ S8)
{
  const int j   = blockIdx.x;
  const int img = j & 511, rh = j >> 9;       // j%8 == img%8 == XCD
  const int tid = threadIdx.x;
  const int w   = tid >> 6;
  const int l   = tid & 63;
  const int lm  = l & 15, lk = l >> 4;

  __shared__ int xt4[1944];                   // xh[3][18][36] + xl (u16 view, 3888 u16)
  __shared__ i32x4 bnc4[4][16][4];            // per-wave spike bounce [16px][64co]
  unsigned short* xs = (unsigned short*)xt4;
  unsigned char*  bnc = (unsigned char*)bnc4;

  for (int i = tid; i < 1944; i += 256) xt4[i] = 0;
  __syncthreads();
  const float* xin = x + (size_t)img * 3072;
  for (int jj = tid; jj < 1728; jj += 256) {  // 3ci x 18 rows x 32 cols
    int ci = jj / 576, rem = jj - ci*576, rl = rem >> 5, c = rem & 31;
    int gr = rh*16 - 1 + rl;
    float f = (gr >= 0 && gr < 32) ? xin[ci*1024 + gr*32 + c] : 0.f;
    __hip_bfloat16 h = __float2bfloat16(f);
    __hip_bfloat16 lo = __float2bfloat16(f - (float)h);
    int idx = ci*648 + rl*36 + (c+1);
    xs[idx] = *(unsigned short*)&h;
    xs[idx + 1944] = *(unsigned short*)&lo;
  }

  // per-lane weight fragments + im2col offsets (k = lk*8+e; k>=27 -> zero weight)
  bf16x8 Wf[2][4];
  float  b1v[4];
  int off16[8];
  #pragma unroll
  for (int e = 0; e < 8; e++) {
    int k = lk*8 + e;
    int s = k/3, ci = k - s*3;
    if (k < 27) { int dr = s/3, dc = s - dr*3; off16[e] = ci*648 + dr*36 + dc; }
    else off16[e] = 0;
    #pragma unroll
    for (int nf = 0; nf < 4; nf++) {
      float wv = (k < 27) ? w1[(nf*16+lm)*27 + ci*9 + s] : 0.f;
      __hip_bfloat16 h = __float2bfloat16(wv);
      __hip_bfloat16 lo = __float2bfloat16(wv - (float)h);
      Wf[0][nf][e] = *(short*)&h;
      Wf[1][nf][e] = *(short*)&lo;
    }
  }
  #pragma unroll
  for (int nf = 0; nf < 4; nf++) b1v[nf] = b1[nf*16 + lm];
  __syncthreads();

  unsigned char* S8b = S8 + (size_t)img * SZ_IMG;
  for (int fi = 0; fi < 8; fi++) {           // 4 waves x 8 iters x 16 px = 512 px (half img)
    const int pxF = w*8 + fi;
    const int lrow = pxF >> 1, colh = pxF & 1;
    const int base16 = lrow*36 + colh*16 + lm;
    bf16x8 ah, al;
    #pragma unroll
    for (int e = 0; e < 8; e++) {
      int idx = base16 + off16[e];
      ah[e] = (short)xs[idx];
      al[e] = (short)xs[idx + 1944];
    }
    f32x4 acc[4] = {};
    #pragma unroll
    for (int nf = 0; nf < 4; nf++) {
      acc[nf] = __builtin_amdgcn_mfma_f32_16x16x32_bf16(ah, Wf[0][nf], acc[nf], 0,0,0);
      acc[nf] = __builtin_amdgcn_mfma_f32_16x16x32_bf16(al, Wf[0][nf], acc[nf], 0,0,0);
      acc[nf] = __builtin_amdgcn_mfma_f32_16x16x32_bf16(ah, Wf[1][nf], acc[nf], 0,0,0);
      acc[nf] = __builtin_amdgcn_mfma_f32_16x16x32_bf16(al, Wf[1][nf], acc[nf], 0,0,0);
    }
    #pragma unroll
    for (int nf = 0; nf < 4; nf++)
      #pragma unroll
      for (int e4 = 0; e4 < 4; e4++) {
        float v = acc[nf][e4] + b1v[nf];
        bnc[w*1024 + (lk*4+e4)*64 + nf*16 + lm] = (v >= 1.2f) ? 1 : 0;
      }
    const int pxl = l >> 2, coq = l & 3;
    i32x4 sp = *(const i32x4*)(bnc + w*1024 + pxl*64 + coq*16);
    const int gcol = colh*16 + pxl;
    const int grow = rh*16 + lrow;
    const int cq = coq ^ SWZ(gcol + 1);
    *(i32x4*)(S8b + (size_t)(grow*32 + gcol)*64 + cq*16) = sp;
  }
}

// ---- conv2 + LIF + count + FUSED FC. 512 blocks (b, 8-row slice, co-half), 512 thr.
// wave = 2 rows x 16 co x both q (rp = wv>>1, cq = wv&1). B streamed from LDS.
// Dynamic LDS: Abuf dbuf [2][10*2176]=43520 + Blds [2q][9s][32co][64ci]=36864 = 80384 B.
// Epilogue: counts -> XOR-skewed bounce -> per-thread 16-px FC dot with wfc -> reduce
// -> 10 atomicAdds per block. cnt never touches global memory.
__global__ __launch_bounds__(512, 2) void conv2fc_k(
    const unsigned char* __restrict__ S8, const signed char* __restrict__ Bq,
    const float* __restrict__ b2, const float* __restrict__ wfc,
    float* __restrict__ out)
{
  extern __shared__ __align__(16) unsigned char lds[];
  unsigned char* Abuf = lds;                  // [2][21760]
  unsigned char* Blds = lds + 43520;          // [q][s][colocal][ci]

  const int j  = blockIdx.x;
  const int b  = j & 63;                      // b%8 == j%8 == conv1's XCD
  const int rs = (j >> 6) & 3;                // 8-row slice
  const int ch = j >> 8;                      // co half
  const int tid = threadIdx.x;
  const int wv = tid >> 6, l = tid & 63;
  const int lm = l & 15, lk = l >> 4;
  const int rp = wv >> 1;                     // row-pair 0..3
  const int cq = wv & 1;                      // co quarter within half
  const int colocal = cq*16 + lm;

  const float b2v = b2[ch*32 + colocal];

  // zero Abuf (pad cols + halo rows stay zero; interior re-staged per t)
  {
    i32x4 z = {0,0,0,0};
    i32x4* ap = (i32x4*)Abuf;
    for (int c = tid; c < 2720; c += 512) ap[c] = z;
  }
  __syncthreads();

  // stage B half (2304 chunks) + A tile t=0 (1280 chunks, rows rs*8-1 .. rs*8+8)
  {
    const signed char* Bsrc = Bq;
    #pragma unroll
    for (int it = 0; it < 5; it++) {
      const int c = it*512 + tid;
      if (c < 2304) {
        const int q = c / 1152, r = c - q*1152, s = r >> 7, r2 = r & 127;
        const int col = r2 >> 2, cic = r2 & 3;
        gl_lds16(Bsrc + q*36864 + s*4096 + (ch*32+col)*64 + cic*16, Blds + c*16);
      }
    }
    const unsigned char* Simg = S8 + (size_t)b*SZ_IMG;
    #pragma unroll
    for (int it = 0; it < 3; it++) {
      const int c = it*512 + tid;
      if (c < 1280) {
        const int row = c >> 7, grow = rs*8 - 1 + row;
        if (grow >= 0 && grow < 32)
          gl_lds16(Simg + grow*2048 + (c&127)*16, Abuf + row*2176 + 64 + (c&127)*16);
      }
    }
  }
  __syncthreads();

  unsigned int cntp[4] = {};

  for (int t = 0; t < 8; t++) {
    if (t < 7) {                              // prefetch t+1 into other buffer
      const unsigned char* Simg = S8 + (size_t)((t+1)*64 + b)*SZ_IMG;
      unsigned char* bufn = Abuf + ((t+1) & 1)*21760;
      #pragma unroll
      for (int it = 0; it < 3; it++) {
        const int c = it*512 + tid;
        if (c < 1280) {
          const int row = c >> 7, grow = rs*8 - 1 + row;
          if (grow >= 0 && grow < 32)
            gl_lds16(Simg + grow*2048 + (c&127)*16, bufn + row*2176 + 64 + (c&127)*16);
        }
      }
    }

    const unsigned char* ab = Abuf + (t & 1)*21760;
    i32x4 acc1[4] = {}, acc2[4] = {};
    __builtin_amdgcn_s_setprio(1);
    #pragma unroll
    for (int s = 0; s < 9; s++) {
      const int dr = s/3, dc = s - dr*3;
      i32x4 Bf1 = *(const i32x4*)(Blds + s*2048 + colocal*64 + lk*16);
      i32x4 Bf2 = *(const i32x4*)(Blds + 18432 + s*2048 + colocal*64 + lk*16);
      #pragma unroll
      for (int a = 0; a < 4; a++) {
        const int lr = rp*2 + (a>>1) + dr;            // 0..9
        const int cp = ((a&1)<<4) + lm + dc;          // 0..33
        i32x4 Af = *(const i32x4*)(ab + lr*2176 + cp*64 + ((lk ^ SWZ(cp)) << 4));
        acc1[a] = __builtin_amdgcn_mfma_i32_16x16x64_i8(Af, Bf1, acc1[a], 0,0,0);
        acc2[a] = __builtin_amdgcn_mfma_i32_16x16x64_i8(Af, Bf2, acc2[a], 0,0,0);
      }
    }
    __builtin_amdgcn_s_setprio(0);

    #pragma unroll
    for (int a = 0; a < 4; a++) {
      unsigned int p = 0;
      #pragma unroll
      for (int e = 0; e < 4; e++) {
        float v = S1Q*(float)acc1[a][e] + S2Q*(float)acc2[a][e] + b2v;
        p |= (v >= 1.2f ? 1u : 0u) << (8*e);
      }
      cntp[a] += p;                           // counts <= 8 per byte, no carry
    }
    __syncthreads();   // drains vmcnt (prefetch landed) + all reads of buf[t&1] done
  }

  // counts -> XOR-skewed bounce in Abuf buf0 (slot = (u>>2)^(co&15), word = u&3)
  unsigned int* bb = (unsigned int*)Abuf;     // [32 colocal][64 u32]
  #pragma unroll
  for (int a = 0; a < 4; a++) {
    const int lrow = rp*2 + (a>>1);           // 0..7
    const int u = lrow*8 + (a&1)*4 + lk;      // px-quad 0..63 (u&3 == lk)
    bb[colocal*64 + (((u>>2) ^ (colocal & 15)) << 2) + (u&3)] = cntp[a];
  }
  __syncthreads();

  // fused FC: thread owns (co = tid>>4, seg = tid&15) -> 16 px starting at seg*16.
  // Skewed slot for quads g = seg*4..seg*4+3 is constant (= seg ^ (co&15)) -> one b128.
  float facc[10];
  {
    const int co = tid >> 4, seg = tid & 15;
    i32x4 cw = *(const i32x4*)(bb + co*64 + ((seg ^ (co & 15)) << 2));
    const unsigned char* cb = (const unsigned char*)&cw;   // 16 px counts
    const size_t ibase = (size_t)(ch*32 + co)*1024 + rs*256 + seg*16;
    #pragma unroll
    for (int o = 0; o < 10; o++) {
      const float* wp = wfc + (size_t)o*65536 + ibase;
      float s0 = 0.f;
      #pragma unroll
      for (int q4 = 0; q4 < 4; q4++) {
        float4 wv4 = *(const float4*)(wp + q4*4);
        s0 += wv4.x*(float)cb[q4*4+0] + wv4.y*(float)cb[q4*4+1]
            + wv4.z*(float)cb[q4*4+2] + wv4.w*(float)cb[q4*4+3];
      }
      facc[o] = s0;
    }
  }
  // wave-reduce then block-reduce (red area beyond the 8KB bounce region)
  #pragma unroll
  for (int o = 0; o < 10; o++) {
    float v = facc[o];
    #pragma unroll
    for (int off = 32; off > 0; off >>= 1) v += __shfl_down(v, off, 64);
    facc[o] = v;
  }
  float* red = (float*)(Abuf + 16384);        // [8 waves][10]
  if (l == 0) {
    #pragma unroll
    for (int o = 0; o < 10; o++) red[wv*10 + o] = facc[o];
  }
  __syncthreads();
  if (tid < 10) {
    float v = 0.f;
    #pragma unroll
    for (int q = 0; q < 8; q++) v += red[q*10 + tid];
    atomicAdd(out + b*10 + tid, v);
  }
}

extern "C" void kernel_launch(void* const* d_in, const int* in_sizes, int n_in,
                              void* d_out, int out_size, void* d_ws, size_t ws_size,
                              hipStream_t stream)
{
  const float* x   = (const float*)d_in[0];
  const float* w1  = (const float*)d_in[1];
  const float* b1  = (const float*)d_in[2];
  const float* w2  = (const float*)d_in[3];
  const float* b2  = (const float*)d_in[4];
  const float* wfc = (const float*)d_in[5];
  const float* bfc = (const float*)d_in[6];
  float* out = (float*)d_out;

  unsigned char* ws  = (unsigned char*)d_ws;
  unsigned char* S8  = ws + OFF_S8;
  signed char*   Bq  = (signed char*)(ws + OFF_BQ);

  kprep<<<144, 256, 0, stream>>>(w2, bfc, Bq, out);
  conv1_k<<<1024, 256, 0, stream>>>(x, w1, b1, S8);
  conv2fc_k<<<512, 512, 80384, stream>>>(S8, Bq, b2, wfc, out);
}